// Round 1
// baseline (352.988 us; speedup 1.0000x reference)
//
#include <hip/hip_runtime.h>

typedef short bf16x8 __attribute__((ext_vector_type(8)));
typedef float f32x4  __attribute__((ext_vector_type(4)));
typedef unsigned int u32;
typedef unsigned short u16;

#define NBATCH 16
#define C      512
#define NPIX   4096
#define ATT_OFF ((size_t)NBATCH * 1024 * NPIX)   // 67,108,864 floats

__device__ __forceinline__ u16 bf16_rn(float x) {
    u32 u = __float_as_uint(x);
    u += 0x7FFFu + ((u >> 16) & 1u);             // round-to-nearest-even
    return (u16)(u >> 16);
}

// ---------------------------------------------------------------------------
// GEMM1: energy[b,i,j] = sum_n x1[b,i,n]*x2[b,j,n]  (split-bf16, 3 MFMA)
// Also copies x1 -> out channels [0,512) (jb==0 blocks).
// Writes energy into d_out's attention slot (softmax'd in-place later).
// ---------------------------------------------------------------------------
__global__ __launch_bounds__(256, 1) void gemm1_energy(
    const float* __restrict__ x1, const float* __restrict__ x2,
    float* __restrict__ out)
{
    __shared__ __align__(16) u16 Ahi[128 * 32];
    __shared__ __align__(16) u16 Alo[128 * 32];
    __shared__ __align__(16) u16 Bhi[128 * 32];
    __shared__ __align__(16) u16 Blo[128 * 32];

    const int tid  = threadIdx.x;
    const int lane = tid & 63;
    const int wid  = tid >> 6;
    const int wr   = (wid >> 1) * 64;   // wave row offset in 128x128 tile
    const int wc   = (wid & 1) * 64;    // wave col offset
    const int r16  = lane & 15;
    const int g    = lane >> 4;

    // XCD-aware bijective swizzle (256 % 8 == 0)
    const int gid = (blockIdx.x & 7) * 32 + (blockIdx.x >> 3);
    const int b   = gid >> 4;
    const int ib  = ((gid >> 2) & 3) * 128;
    const int jb  = (gid & 3) * 128;

    const int srow = tid >> 3;          // staging row 0..31 (chunk adds c*32)
    const int sc   = (tid & 7) * 4;     // f32 col within BK=32

    const float* Ab = x1 + (size_t)(b * C + ib + srow) * NPIX + sc;
    const float* Bb = x2 + (size_t)(b * C + jb + srow) * NPIX + sc;
    float* cpy = out + (size_t)(b * 1024 + ib + srow) * NPIX + sc;

    f32x4 pa[4], pb[4];
    #pragma unroll
    for (int c = 0; c < 4; ++c) {
        pa[c] = *(const f32x4*)(Ab + (size_t)c * 32 * NPIX);
        pb[c] = *(const f32x4*)(Bb + (size_t)c * 32 * NPIX);
    }

    const f32x4 zero4 = {0.f, 0.f, 0.f, 0.f};
    f32x4 acc[4][4];
    #pragma unroll
    for (int i = 0; i < 4; ++i)
        #pragma unroll
        for (int j = 0; j < 4; ++j) acc[i][j] = zero4;

    const int wb = (tid & 7) * 8;       // byte col of 4-elem pair in 64B row

    for (int kt = 0; kt < 128; ++kt) {
        __syncthreads();                // previous compute done, LDS free
        #pragma unroll
        for (int c = 0; c < 4; ++c) {
            const int row = srow + c * 32;
            const int sw  = (row * 64 + wb) ^ ((row & 2) << 3);
            u32 h[4], l[4];
            #pragma unroll
            for (int k = 0; k < 4; ++k) {           // split A
                u32 u  = __float_as_uint(pa[c][k]);
                u32 hb = (u + 0x8000u) & 0xFFFF0000u;
                h[k] = hb >> 16;
                float lf = pa[c][k] - __uint_as_float(hb);
                l[k] = __float_as_uint(lf) >> 16;
            }
            *(uint2*)((char*)Ahi + sw) = make_uint2(h[0] | (h[1] << 16), h[2] | (h[3] << 16));
            *(uint2*)((char*)Alo + sw) = make_uint2(l[0] | (l[1] << 16), l[2] | (l[3] << 16));
            #pragma unroll
            for (int k = 0; k < 4; ++k) {           // split B
                u32 u  = __float_as_uint(pb[c][k]);
                u32 hb = (u + 0x8000u) & 0xFFFF0000u;
                h[k] = hb >> 16;
                float lf = pb[c][k] - __uint_as_float(hb);
                l[k] = __float_as_uint(lf) >> 16;
            }
            *(uint2*)((char*)Bhi + sw) = make_uint2(h[0] | (h[1] << 16), h[2] | (h[3] << 16));
            *(uint2*)((char*)Blo + sw) = make_uint2(l[0] | (l[1] << 16), l[2] | (l[3] << 16));
            if (jb == 0)                            // fused x1 -> out copy
                *(f32x4*)(cpy + (size_t)c * 32 * NPIX + kt * 32) = pa[c];
        }
        if (kt + 1 < 128) {                          // register prefetch
            #pragma unroll
            for (int c = 0; c < 4; ++c) {
                pa[c] = *(const f32x4*)(Ab + (size_t)c * 32 * NPIX + (kt + 1) * 32);
                pb[c] = *(const f32x4*)(Bb + (size_t)c * 32 * NPIX + (kt + 1) * 32);
            }
        }
        __syncthreads();                // LDS staged

        bf16x8 ah[4], al[4], bh[4], bl[4];
        #pragma unroll
        for (int f = 0; f < 4; ++f) {
            const int ar   = wr + f * 16 + r16;
            const int aoff = (ar * 64 + g * 16) ^ ((ar & 2) << 3);
            ah[f] = *(const bf16x8*)((const char*)Ahi + aoff);
            al[f] = *(const bf16x8*)((const char*)Alo + aoff);
            const int br   = wc + f * 16 + r16;
            const int boff = (br * 64 + g * 16) ^ ((br & 2) << 3);
            bh[f] = *(const bf16x8*)((const char*)Bhi + boff);
            bl[f] = *(const bf16x8*)((const char*)Blo + boff);
        }
        #pragma unroll
        for (int fi = 0; fi < 4; ++fi)
            #pragma unroll
            for (int fj = 0; fj < 4; ++fj) {
                acc[fi][fj] = __builtin_amdgcn_mfma_f32_16x16x32_bf16(ah[fi], bh[fj], acc[fi][fj], 0, 0, 0);
                acc[fi][fj] = __builtin_amdgcn_mfma_f32_16x16x32_bf16(ah[fi], bl[fj], acc[fi][fj], 0, 0, 0);
                acc[fi][fj] = __builtin_amdgcn_mfma_f32_16x16x32_bf16(al[fi], bh[fj], acc[fi][fj], 0, 0, 0);
            }
    }

    float* att = out + ATT_OFF + (size_t)b * C * C;
    #pragma unroll
    for (int fi = 0; fi < 4; ++fi)
        #pragma unroll
        for (int fj = 0; fj < 4; ++fj) {
            const int j = jb + wc + fj * 16 + r16;
            #pragma unroll
            for (int q = 0; q < 4; ++q) {
                const int i = ib + wr + fi * 16 + g * 4 + q;
                att[(size_t)i * C + j] = acc[fi][fj][q];
            }
        }
}

// ---------------------------------------------------------------------------
// Softmax over last dim (512), in place on the attention slot of d_out.
// One 256-thread block per row.
// ---------------------------------------------------------------------------
__global__ __launch_bounds__(256) void softmax_rows(float* __restrict__ att)
{
    float* p = att + (size_t)blockIdx.x * C;
    const int t = threadIdx.x;
    const int lane = t & 63, wid = t >> 6;
    __shared__ float red[8];

    float a = p[t], c = p[t + 256];
    float m = fmaxf(a, c);
    #pragma unroll
    for (int o = 32; o; o >>= 1) m = fmaxf(m, __shfl_xor(m, o));
    if (lane == 0) red[wid] = m;
    __syncthreads();
    m = fmaxf(fmaxf(red[0], red[1]), fmaxf(red[2], red[3]));

    float e0 = __expf(a - m), e1 = __expf(c - m);
    float s = e0 + e1;
    #pragma unroll
    for (int o = 32; o; o >>= 1) s += __shfl_xor(s, o);
    if (lane == 0) red[4 + wid] = s;
    __syncthreads();
    s = (red[4] + red[5]) + (red[6] + red[7]);
    const float inv = 1.0f / s;
    p[t]       = e0 * inv;
    p[t + 256] = e1 * inv;
}

// ---------------------------------------------------------------------------
// GEMM2: av[b,j,n] = sum_i att[b,i,j] * x1[b,i,n]   (TN, K=512, bf16 MFMA)
// LDS-free: K-strided fragment elements loaded straight from L2 (64B segs).
// ---------------------------------------------------------------------------
__global__ __launch_bounds__(256, 2) void gemm2_av(
    const float* __restrict__ x1, float* __restrict__ out)
{
    const float* att = out + ATT_OFF;
    const int tid  = threadIdx.x;
    const int lane = tid & 63;
    const int wid  = tid >> 6;
    const int wr   = (wid >> 1) * 64;
    const int wc   = (wid & 1) * 64;
    const int r16  = lane & 15;
    const int g    = lane >> 4;

    const int gid = (blockIdx.x & 7) * 256 + (blockIdx.x >> 3);  // XCD swizzle
    const int b   = gid >> 7;
    const int jb  = ((gid >> 5) & 3) * 128;
    const int nb  = (gid & 31) * 128;

    const float* ap = att + (size_t)b * C * C   + jb + wr + r16;  // + k*C + f*16
    const float* bp = x1  + (size_t)b * C * NPIX + nb + wc + r16; // + k*NPIX + f*16

    const f32x4 zero4 = {0.f, 0.f, 0.f, 0.f};
    f32x4 acc[4][4];
    #pragma unroll
    for (int i = 0; i < 4; ++i)
        #pragma unroll
        for (int j = 0; j < 4; ++j) acc[i][j] = zero4;

    for (int kt = 0; kt < 16; ++kt) {
        const int k0 = kt * 32 + g * 8;
        bf16x8 af[4], bfr[4];
        #pragma unroll
        for (int f = 0; f < 4; ++f) {
            #pragma unroll
            for (int e = 0; e < 8; ++e) {
                af[f][e]  = (short)bf16_rn(ap[(size_t)(k0 + e) * C    + f * 16]);
                bfr[f][e] = (short)bf16_rn(bp[(size_t)(k0 + e) * NPIX + f * 16]);
            }
        }
        #pragma unroll
        for (int fi = 0; fi < 4; ++fi)
            #pragma unroll
            for (int fj = 0; fj < 4; ++fj)
                acc[fi][fj] = __builtin_amdgcn_mfma_f32_16x16x32_bf16(af[fi], bfr[fj], acc[fi][fj], 0, 0, 0);
    }

    #pragma unroll
    for (int fi = 0; fi < 4; ++fi)
        #pragma unroll
        for (int fj = 0; fj < 4; ++fj) {
            const int n = nb + wc + fj * 16 + r16;
            #pragma unroll
            for (int q = 0; q < 4; ++q) {
                const int j = jb + wr + fi * 16 + g * 4 + q;
                out[(size_t)(b * 1024 + 512 + j) * NPIX + n] = acc[fi][fj][q];
            }
        }
}

extern "C" void kernel_launch(void* const* d_in, const int* in_sizes, int n_in,
                              void* d_out, int out_size, void* d_ws, size_t ws_size,
                              hipStream_t stream) {
    const float* x1 = (const float*)d_in[0];
    const float* x2 = (const float*)d_in[1];
    float* out = (float*)d_out;
    (void)in_sizes; (void)n_in; (void)out_size; (void)d_ws; (void)ws_size;

    gemm1_energy<<<dim3(256),  dim3(256), 0, stream>>>(x1, x2, out);
    softmax_rows<<<dim3(8192), dim3(256), 0, stream>>>(out + ATT_OFF);
    gemm2_av    <<<dim3(2048), dim3(256), 0, stream>>>(x1, out);
}

// Round 2
// 323.536 us; speedup vs baseline: 1.0910x; 1.0910x over previous
//
#include <hip/hip_runtime.h>

typedef short bf16x8 __attribute__((ext_vector_type(8)));
typedef float f32x4  __attribute__((ext_vector_type(4)));
typedef unsigned int u32;
typedef unsigned short u16;

#define NBATCH 16
#define C      512
#define NPIX   4096
#define ATT_OFF ((size_t)NBATCH * 1024 * NPIX)   // 67,108,864 floats

// ---------------------------------------------------------------------------
// GEMM1: energy[b,i,j] = sum_n x1[b,i,n]*x2[b,j,n]  (split-bf16, 3 MFMA)
// Double-buffered LDS, 1 barrier/kt, 2-way-swizzled LDS layout.
// Each block also copies 1/4 of its A-tile rows to out channels [0,512).
// ---------------------------------------------------------------------------
__global__ __launch_bounds__(256, 1) void gemm1_energy(
    const float* __restrict__ x1, const float* __restrict__ x2,
    float* __restrict__ out)
{
    __shared__ __align__(16) u16 Ahi[2][128 * 32];
    __shared__ __align__(16) u16 Alo[2][128 * 32];
    __shared__ __align__(16) u16 Bhi[2][128 * 32];
    __shared__ __align__(16) u16 Blo[2][128 * 32];

    const int tid  = threadIdx.x;
    const int lane = tid & 63;
    const int wid  = tid >> 6;
    const int wr   = (wid >> 1) * 64;   // wave row offset in 128x128 tile
    const int wc   = (wid & 1) * 64;    // wave col offset
    const int r16  = lane & 15;
    const int g    = lane >> 4;

    // XCD-aware bijective swizzle (256 % 8 == 0)
    const int gid = (blockIdx.x & 7) * 32 + (blockIdx.x >> 3);
    const int b   = gid >> 4;
    const int ib  = ((gid >> 2) & 3) * 128;
    const int jb  = (gid & 3) * 128;

    const int nr = tid >> 2;            // 0..63 (row within half-tile)
    const int kq = tid & 3;             // k-octet (8 f32) within BK=32

    const float* Ab = x1 + (size_t)(b * C + ib + nr) * NPIX + kq * 8;
    const float* Bb = x2 + (size_t)(b * C + jb + nr) * NPIX + kq * 8;
    float* cpyA = out + (size_t)(b * 1024 + ib + nr) * NPIX + kq * 8;
    const int csel = jb >> 7;           // which row-quarter this block copies

    f32x4 pa[2][2], pb[2][2];

    auto loadk = [&](int kt) {
        const int off = kt * 32;
        #pragma unroll
        for (int c = 0; c < 2; ++c) {
            pa[c][0] = *(const f32x4*)(Ab + (size_t)c * 64 * NPIX + off);
            pa[c][1] = *(const f32x4*)(Ab + (size_t)c * 64 * NPIX + off + 4);
            pb[c][0] = *(const f32x4*)(Bb + (size_t)c * 64 * NPIX + off);
            pb[c][1] = *(const f32x4*)(Bb + (size_t)c * 64 * NPIX + off + 4);
        }
    };

    auto stage = [&](int kt, int buf) {
        #pragma unroll
        for (int c = 0; c < 2; ++c) {
            const int row = nr + c * 64;
            const u32 sw = (u32)((row * 64 + kq * 16) ^ (((row >> 1) & 3) << 4));
            u32 ahp[4], alp[4], bhp[4], blp[4];
            #pragma unroll
            for (int p = 0; p < 4; ++p) {
                const float fa0 = pa[c][p >> 1][(p & 1) * 2];
                const float fa1 = pa[c][p >> 1][(p & 1) * 2 + 1];
                const u32 ua0 = __float_as_uint(fa0), ua1 = __float_as_uint(fa1);
                const float la0 = fa0 - __uint_as_float(ua0 & 0xFFFF0000u);
                const float la1 = fa1 - __uint_as_float(ua1 & 0xFFFF0000u);
                ahp[p] = __builtin_amdgcn_perm(ua1, ua0, 0x07060302u);
                alp[p] = __builtin_amdgcn_perm(__float_as_uint(la1), __float_as_uint(la0), 0x07060302u);
                const float fb0 = pb[c][p >> 1][(p & 1) * 2];
                const float fb1 = pb[c][p >> 1][(p & 1) * 2 + 1];
                const u32 ub0 = __float_as_uint(fb0), ub1 = __float_as_uint(fb1);
                const float lb0 = fb0 - __uint_as_float(ub0 & 0xFFFF0000u);
                const float lb1 = fb1 - __uint_as_float(ub1 & 0xFFFF0000u);
                bhp[p] = __builtin_amdgcn_perm(ub1, ub0, 0x07060302u);
                blp[p] = __builtin_amdgcn_perm(__float_as_uint(lb1), __float_as_uint(lb0), 0x07060302u);
            }
            *(uint4*)((char*)Ahi[buf] + sw) = make_uint4(ahp[0], ahp[1], ahp[2], ahp[3]);
            *(uint4*)((char*)Alo[buf] + sw) = make_uint4(alp[0], alp[1], alp[2], alp[3]);
            *(uint4*)((char*)Bhi[buf] + sw) = make_uint4(bhp[0], bhp[1], bhp[2], bhp[3]);
            *(uint4*)((char*)Blo[buf] + sw) = make_uint4(blp[0], blp[1], blp[2], blp[3]);
            if ((row >> 5) == csel) {   // balanced fused x1 -> out copy
                *(f32x4*)(cpyA + (size_t)c * 64 * NPIX + kt * 32)     = pa[c][0];
                *(f32x4*)(cpyA + (size_t)c * 64 * NPIX + kt * 32 + 4) = pa[c][1];
            }
        }
    };

    const f32x4 zero4 = {0.f, 0.f, 0.f, 0.f};
    f32x4 acc[4][4];
    #pragma unroll
    for (int i = 0; i < 4; ++i)
        #pragma unroll
        for (int j = 0; j < 4; ++j) acc[i][j] = zero4;

    loadk(0);
    stage(0, 0);

    for (int kt = 0; kt < 128; ++kt) {
        if (kt < 127) loadk(kt + 1);          // global prefetch, in flight across barrier
        __syncthreads();                      // LDS[kt&1] fully staged
        const int buf = kt & 1;

        bf16x8 ah[4], al[4], bh[4], bl[4];
        #pragma unroll
        for (int f = 0; f < 4; ++f) {
            const int ar = wr + f * 16 + r16;
            const u32 ao = (u32)((ar * 64 + g * 16) ^ (((ar >> 1) & 3) << 4));
            ah[f] = *(const bf16x8*)((const char*)Ahi[buf] + ao);
            al[f] = *(const bf16x8*)((const char*)Alo[buf] + ao);
            const int br = wc + f * 16 + r16;
            const u32 bo = (u32)((br * 64 + g * 16) ^ (((br >> 1) & 3) << 4));
            bh[f] = *(const bf16x8*)((const char*)Bhi[buf] + bo);
            bl[f] = *(const bf16x8*)((const char*)Blo[buf] + bo);
        }
        #pragma unroll
        for (int fi = 0; fi < 4; ++fi)
            #pragma unroll
            for (int fj = 0; fj < 4; ++fj) {
                acc[fi][fj] = __builtin_amdgcn_mfma_f32_16x16x32_bf16(ah[fi], bh[fj], acc[fi][fj], 0, 0, 0);
                acc[fi][fj] = __builtin_amdgcn_mfma_f32_16x16x32_bf16(ah[fi], bl[fj], acc[fi][fj], 0, 0, 0);
                acc[fi][fj] = __builtin_amdgcn_mfma_f32_16x16x32_bf16(al[fi], bh[fj], acc[fi][fj], 0, 0, 0);
            }
        if (kt < 127) stage(kt + 1, buf ^ 1); // write other buffer (safe post-barrier)
    }

    float* att = out + ATT_OFF + (size_t)b * C * C;
    #pragma unroll
    for (int fi = 0; fi < 4; ++fi)
        #pragma unroll
        for (int fj = 0; fj < 4; ++fj) {
            const int j = jb + wc + fj * 16 + r16;
            #pragma unroll
            for (int q = 0; q < 4; ++q) {
                const int i = ib + wr + fi * 16 + g * 4 + q;
                att[(size_t)i * C + j] = acc[fi][fj][q];
            }
        }
}

// ---------------------------------------------------------------------------
// Softmax over last dim (512), in place on the attention slot of d_out.
// ---------------------------------------------------------------------------
__global__ __launch_bounds__(256) void softmax_rows(float* __restrict__ att)
{
    float* p = att + (size_t)blockIdx.x * C;
    const int t = threadIdx.x;
    const int lane = t & 63, wid = t >> 6;
    __shared__ float red[8];

    float a = p[t], c = p[t + 256];
    float m = fmaxf(a, c);
    #pragma unroll
    for (int o = 32; o; o >>= 1) m = fmaxf(m, __shfl_xor(m, o));
    if (lane == 0) red[wid] = m;
    __syncthreads();
    m = fmaxf(fmaxf(red[0], red[1]), fmaxf(red[2], red[3]));

    float e0 = __expf(a - m), e1 = __expf(c - m);
    float s = e0 + e1;
    #pragma unroll
    for (int o = 32; o; o >>= 1) s += __shfl_xor(s, o);
    if (lane == 0) red[4 + wid] = s;
    __syncthreads();
    s = (red[4] + red[5]) + (red[6] + red[7]);
    const float inv = 1.0f / s;
    p[t]       = e0 * inv;
    p[t + 256] = e1 * inv;
}

// ---------------------------------------------------------------------------
// GEMM2: av[b,j,n] = sum_i att[b,i,j] * x1[b,i,n]   (TN, K=512, bf16 MFMA)
// LDS-free register-direct loads; truncation converts (1 VALU op each).
// ---------------------------------------------------------------------------
__global__ __launch_bounds__(256, 2) void gemm2_av(
    const float* __restrict__ x1, float* __restrict__ out)
{
    const float* att = out + ATT_OFF;
    const int tid  = threadIdx.x;
    const int lane = tid & 63;
    const int wid  = tid >> 6;
    const int wr   = (wid >> 1) * 64;
    const int wc   = (wid & 1) * 64;
    const int r16  = lane & 15;
    const int g    = lane >> 4;

    const int gid = (blockIdx.x & 7) * 256 + (blockIdx.x >> 3);  // XCD swizzle
    const int b   = gid >> 7;
    const int jb  = ((gid >> 5) & 3) * 128;
    const int nb  = (gid & 31) * 128;

    const float* ap = att + (size_t)b * C * C    + jb + wr + r16;  // + k*C + f*16
    const float* bp = x1  + (size_t)b * C * NPIX + nb + wc + r16;  // + k*NPIX + f*16

    const f32x4 zero4 = {0.f, 0.f, 0.f, 0.f};
    f32x4 acc[4][4];
    #pragma unroll
    for (int i = 0; i < 4; ++i)
        #pragma unroll
        for (int j = 0; j < 4; ++j) acc[i][j] = zero4;

    for (int kt = 0; kt < 16; ++kt) {
        const int k0 = kt * 32 + g * 8;
        bf16x8 af[4], bfr[4];
        #pragma unroll
        for (int f = 0; f < 4; ++f) {
            #pragma unroll
            for (int e = 0; e < 8; ++e) {
                af[f][e]  = (short)(u16)(__float_as_uint(ap[(size_t)(k0 + e) * C    + f * 16]) >> 16);
                bfr[f][e] = (short)(u16)(__float_as_uint(bp[(size_t)(k0 + e) * NPIX + f * 16]) >> 16);
            }
        }
        #pragma unroll
        for (int fi = 0; fi < 4; ++fi)
            #pragma unroll
            for (int fj = 0; fj < 4; ++fj)
                acc[fi][fj] = __builtin_amdgcn_mfma_f32_16x16x32_bf16(af[fi], bfr[fj], acc[fi][fj], 0, 0, 0);
    }

    #pragma unroll
    for (int fi = 0; fi < 4; ++fi)
        #pragma unroll
        for (int fj = 0; fj < 4; ++fj) {
            const int n = nb + wc + fj * 16 + r16;
            #pragma unroll
            for (int q = 0; q < 4; ++q) {
                const int j = jb + wr + fi * 16 + g * 4 + q;
                out[(size_t)(b * 1024 + 512 + j) * NPIX + n] = acc[fi][fj][q];
            }
        }
}

extern "C" void kernel_launch(void* const* d_in, const int* in_sizes, int n_in,
                              void* d_out, int out_size, void* d_ws, size_t ws_size,
                              hipStream_t stream) {
    const float* x1 = (const float*)d_in[0];
    const float* x2 = (const float*)d_in[1];
    float* out = (float*)d_out;
    (void)in_sizes; (void)n_in; (void)out_size; (void)d_ws; (void)ws_size;

    gemm1_energy<<<dim3(256),  dim3(256), 0, stream>>>(x1, x2, out);
    softmax_rows<<<dim3(8192), dim3(256), 0, stream>>>(out + ATT_OFF);
    gemm2_av    <<<dim3(2048), dim3(256), 0, stream>>>(x1, out);
}

// Round 3
// 272.922 us; speedup vs baseline: 1.2934x; 1.1855x over previous
//
#include <hip/hip_runtime.h>

typedef short bf16x8 __attribute__((ext_vector_type(8)));
typedef float f32x4  __attribute__((ext_vector_type(4)));
typedef unsigned int u32;
typedef unsigned short u16;

#define NBATCH 16
#define C      512
#define NPIX   4096
#define ATT_OFF ((size_t)NBATCH * 1024 * NPIX)   // 67,108,864 floats

// ---------------------------------------------------------------------------
// GEMM1: energy[b,i,j] = sum_n x1[b,i,n]*x2[b,j,n]  (split-bf16, 3 MFMA)
// 512 threads = 2 k-teams x 4 waves; in-block split-K (team t: k in
// [t*2048,(t+1)*2048)); each team double-buffers its own 64KB LDS half.
// Final LDS f32 reduce. Each block also copies 1/4 of its A-rows to out.
// ---------------------------------------------------------------------------
__global__ __launch_bounds__(512, 2) void gemm1_energy(
    const float* __restrict__ x1, const float* __restrict__ x2,
    float* __restrict__ out)
{
    // [team][buf][array(Ahi,Alo,Bhi,Blo)][128*32] = 128 KiB
    __shared__ __align__(16) u16 smem[2][2][4][128 * 32];

    const int tid  = threadIdx.x;
    const int team = tid >> 8;
    const int ttid = tid & 255;
    const int lane = tid & 63;
    const int w    = (tid >> 6) & 3;    // wave within team
    const int wr   = (w >> 1) * 64;
    const int wc   = (w & 1) * 64;
    const int r16  = lane & 15;
    const int g    = lane >> 4;

    const int gid = (blockIdx.x & 7) * 32 + (blockIdx.x >> 3);  // XCD swizzle
    const int b   = gid >> 4;
    const int ib  = ((gid >> 2) & 3) * 128;
    const int jb  = (gid & 3) * 128;

    const int nr = ttid >> 2;           // 0..63 (row within half-tile)
    const int kq = ttid & 3;            // k-octet (8 f32) within BK=32
    const int ko = team * 2048;         // team k-offset

    const float* Ab = x1 + (size_t)(b * C + ib + nr) * NPIX + ko + kq * 8;
    const float* Bb = x2 + (size_t)(b * C + jb + nr) * NPIX + ko + kq * 8;
    float* cpyA = out + (size_t)(b * 1024 + ib + nr) * NPIX + ko + kq * 8;
    const int csel = jb >> 7;           // which row-quarter this block copies

    f32x4 pa[2][2], pb[2][2];

    auto loadk = [&](int kt) {
        const int off = kt * 32;
        #pragma unroll
        for (int c = 0; c < 2; ++c) {
            pa[c][0] = *(const f32x4*)(Ab + (size_t)c * 64 * NPIX + off);
            pa[c][1] = *(const f32x4*)(Ab + (size_t)c * 64 * NPIX + off + 4);
            pb[c][0] = *(const f32x4*)(Bb + (size_t)c * 64 * NPIX + off);
            pb[c][1] = *(const f32x4*)(Bb + (size_t)c * 64 * NPIX + off + 4);
        }
    };

    auto stage = [&](int kt, int buf) {
        #pragma unroll
        for (int c = 0; c < 2; ++c) {
            const int row = nr + c * 64;
            const u32 sw = (u32)((row * 64 + kq * 16) ^ (((row >> 1) & 3) << 4));
            u32 ahp[4], alp[4], bhp[4], blp[4];
            #pragma unroll
            for (int p = 0; p < 4; ++p) {
                const float fa0 = pa[c][p >> 1][(p & 1) * 2];
                const float fa1 = pa[c][p >> 1][(p & 1) * 2 + 1];
                const u32 ua0 = __float_as_uint(fa0), ua1 = __float_as_uint(fa1);
                const float la0 = fa0 - __uint_as_float(ua0 & 0xFFFF0000u);
                const float la1 = fa1 - __uint_as_float(ua1 & 0xFFFF0000u);
                ahp[p] = __builtin_amdgcn_perm(ua1, ua0, 0x07060302u);
                alp[p] = __builtin_amdgcn_perm(__float_as_uint(la1), __float_as_uint(la0), 0x07060302u);
                const float fb0 = pb[c][p >> 1][(p & 1) * 2];
                const float fb1 = pb[c][p >> 1][(p & 1) * 2 + 1];
                const u32 ub0 = __float_as_uint(fb0), ub1 = __float_as_uint(fb1);
                const float lb0 = fb0 - __uint_as_float(ub0 & 0xFFFF0000u);
                const float lb1 = fb1 - __uint_as_float(ub1 & 0xFFFF0000u);
                bhp[p] = __builtin_amdgcn_perm(ub1, ub0, 0x07060302u);
                blp[p] = __builtin_amdgcn_perm(__float_as_uint(lb1), __float_as_uint(lb0), 0x07060302u);
            }
            *(uint4*)((char*)smem[team][buf][0] + sw) = make_uint4(ahp[0], ahp[1], ahp[2], ahp[3]);
            *(uint4*)((char*)smem[team][buf][1] + sw) = make_uint4(alp[0], alp[1], alp[2], alp[3]);
            *(uint4*)((char*)smem[team][buf][2] + sw) = make_uint4(bhp[0], bhp[1], bhp[2], bhp[3]);
            *(uint4*)((char*)smem[team][buf][3] + sw) = make_uint4(blp[0], blp[1], blp[2], blp[3]);
            if ((row >> 5) == csel) {   // balanced fused x1 -> out copy
                *(f32x4*)(cpyA + (size_t)c * 64 * NPIX + kt * 32)     = pa[c][0];
                *(f32x4*)(cpyA + (size_t)c * 64 * NPIX + kt * 32 + 4) = pa[c][1];
            }
        }
    };

    const f32x4 zero4 = {0.f, 0.f, 0.f, 0.f};
    f32x4 acc[4][4];
    #pragma unroll
    for (int i = 0; i < 4; ++i)
        #pragma unroll
        for (int j = 0; j < 4; ++j) acc[i][j] = zero4;

    loadk(0);
    stage(0, 0);

    for (int kt = 0; kt < 64; ++kt) {
        if (kt < 63) loadk(kt + 1);           // global prefetch across barrier
        __syncthreads();
        const int buf = kt & 1;

        bf16x8 ah[4], al[4], bh[4], bl[4];
        #pragma unroll
        for (int f = 0; f < 4; ++f) {
            const int ar = wr + f * 16 + r16;
            const u32 ao = (u32)((ar * 64 + g * 16) ^ (((ar >> 1) & 3) << 4));
            ah[f] = *(const bf16x8*)((const char*)smem[team][buf][0] + ao);
            al[f] = *(const bf16x8*)((const char*)smem[team][buf][1] + ao);
            const int br = wc + f * 16 + r16;
            const u32 bo = (u32)((br * 64 + g * 16) ^ (((br >> 1) & 3) << 4));
            bh[f] = *(const bf16x8*)((const char*)smem[team][buf][2] + bo);
            bl[f] = *(const bf16x8*)((const char*)smem[team][buf][3] + bo);
        }
        #pragma unroll
        for (int fi = 0; fi < 4; ++fi)
            #pragma unroll
            for (int fj = 0; fj < 4; ++fj) {
                acc[fi][fj] = __builtin_amdgcn_mfma_f32_16x16x32_bf16(ah[fi], bh[fj], acc[fi][fj], 0, 0, 0);
                acc[fi][fj] = __builtin_amdgcn_mfma_f32_16x16x32_bf16(ah[fi], bl[fj], acc[fi][fj], 0, 0, 0);
                acc[fi][fj] = __builtin_amdgcn_mfma_f32_16x16x32_bf16(al[fi], bh[fj], acc[fi][fj], 0, 0, 0);
            }
        if (kt < 63) stage(kt + 1, buf ^ 1);
    }

    // cross-team reduction through LDS (team1 -> team0)
    __syncthreads();
    f32x4* red = (f32x4*)&smem[0][0][0][0];   // 64 KiB of the 128 KiB pool
    const int slot = w * 64 + lane;           // 0..255 within team
    if (team == 1) {
        #pragma unroll
        for (int c = 0; c < 16; ++c) red[c * 256 + slot] = acc[c >> 2][c & 3];
    }
    __syncthreads();
    if (team == 0) {
        float* att = out + ATT_OFF + (size_t)b * C * C;
        #pragma unroll
        for (int fi = 0; fi < 4; ++fi)
            #pragma unroll
            for (int fj = 0; fj < 4; ++fj) {
                f32x4 v = acc[fi][fj];
                const f32x4 o = red[(fi * 4 + fj) * 256 + slot];
                const int j = jb + wc + fj * 16 + r16;
                #pragma unroll
                for (int q = 0; q < 4; ++q) {
                    const int i = ib + wr + fi * 16 + g * 4 + q;
                    att[(size_t)i * C + j] = v[q] + o[q];
                }
            }
    }
}

// ---------------------------------------------------------------------------
// Softmax over last dim (512), in place on the attention slot of d_out.
// ---------------------------------------------------------------------------
__global__ __launch_bounds__(256) void softmax_rows(float* __restrict__ att)
{
    float* p = att + (size_t)blockIdx.x * C;
    const int t = threadIdx.x;
    const int lane = t & 63, wid = t >> 6;
    __shared__ float red[8];

    float a = p[t], c = p[t + 256];
    float m = fmaxf(a, c);
    #pragma unroll
    for (int o = 32; o; o >>= 1) m = fmaxf(m, __shfl_xor(m, o));
    if (lane == 0) red[wid] = m;
    __syncthreads();
    m = fmaxf(fmaxf(red[0], red[1]), fmaxf(red[2], red[3]));

    float e0 = __expf(a - m), e1 = __expf(c - m);
    float s = e0 + e1;
    #pragma unroll
    for (int o = 32; o; o >>= 1) s += __shfl_xor(s, o);
    if (lane == 0) red[4 + wid] = s;
    __syncthreads();
    s = (red[4] + red[5]) + (red[6] + red[7]);
    const float inv = 1.0f / s;
    p[t]       = e0 * inv;
    p[t + 256] = e1 * inv;
}

// ---------------------------------------------------------------------------
// GEMM2: av[b,j,n] = sum_k att[b,k,j] * x1[b,k,n]   (TT, K=512, bf16 MFMA)
// LDS-staged with transpose-on-store: tiles [row][32k] bf16, row stride 36
// u16. Double-buffered, 2048 blocks (3/CU).
// ---------------------------------------------------------------------------
#define KST 36   // u16 stride per LDS row (32 + 4 pad)

__global__ __launch_bounds__(256, 3) void gemm2_av(
    const float* __restrict__ x1, float* __restrict__ out)
{
    __shared__ __align__(16) u16 Aj[2][128 * KST];  // att^T tile: row j, k 0..31
    __shared__ __align__(16) u16 Bn[2][128 * KST];  // x1^T tile: row n, k 0..31

    const float* att = out + ATT_OFF;
    const int tid  = threadIdx.x;
    const int lane = tid & 63;
    const int wid  = tid >> 6;
    const int wr   = (wid >> 1) * 64;   // j
    const int wc   = (wid & 1) * 64;    // n
    const int r16  = lane & 15;
    const int g    = lane >> 4;

    const int gid = (blockIdx.x & 7) * 256 + (blockIdx.x >> 3);  // XCD swizzle
    const int b   = gid >> 7;
    const int jt  = (gid >> 5) & 3;
    const int nt  = gid & 31;
    const int jb  = jt * 128;
    const int nb  = nt * 128;

    const int col = (tid & 31) * 4;     // j (or n) column group staged
    const int ks  = (tid >> 5) * 4;     // 4 k's per thread per tile

    const float* ap0 = att + (size_t)b * C * C    + (size_t)ks * C    + jb + col;
    const float* bp0 = x1  + (size_t)b * C * NPIX + (size_t)ks * NPIX + nb + col;

    u32 sa[8], sb[8];                   // packed bf16 pairs, pre-staged

    auto loadpack = [&](int kt) {
        f32x4 L[4];
        #pragma unroll
        for (int i = 0; i < 4; ++i) L[i] = *(const f32x4*)(ap0 + (size_t)(kt * 32 + i) * C);
        #pragma unroll
        for (int jj = 0; jj < 4; ++jj) {
            sa[jj * 2]     = __builtin_amdgcn_perm(__float_as_uint(L[1][jj]), __float_as_uint(L[0][jj]), 0x07060302u);
            sa[jj * 2 + 1] = __builtin_amdgcn_perm(__float_as_uint(L[3][jj]), __float_as_uint(L[2][jj]), 0x07060302u);
        }
        #pragma unroll
        for (int i = 0; i < 4; ++i) L[i] = *(const f32x4*)(bp0 + (size_t)(kt * 32 + i) * NPIX);
        #pragma unroll
        for (int jj = 0; jj < 4; ++jj) {
            sb[jj * 2]     = __builtin_amdgcn_perm(__float_as_uint(L[1][jj]), __float_as_uint(L[0][jj]), 0x07060302u);
            sb[jj * 2 + 1] = __builtin_amdgcn_perm(__float_as_uint(L[3][jj]), __float_as_uint(L[2][jj]), 0x07060302u);
        }
    };

    auto stage = [&](int buf) {
        #pragma unroll
        for (int jj = 0; jj < 4; ++jj) {
            *(uint2*)((char*)Aj[buf] + ((col + jj) * KST + ks) * 2) = make_uint2(sa[jj * 2], sa[jj * 2 + 1]);
            *(uint2*)((char*)Bn[buf] + ((col + jj) * KST + ks) * 2) = make_uint2(sb[jj * 2], sb[jj * 2 + 1]);
        }
    };

    const f32x4 zero4 = {0.f, 0.f, 0.f, 0.f};
    f32x4 acc[4][4];
    #pragma unroll
    for (int i = 0; i < 4; ++i)
        #pragma unroll
        for (int j = 0; j < 4; ++j) acc[i][j] = zero4;

    loadpack(0);
    stage(0);

    for (int kt = 0; kt < 16; ++kt) {
        if (kt < 15) loadpack(kt + 1);
        __syncthreads();
        const int buf = kt & 1;

        union { bf16x8 v; uint2 u2[2]; } fa[4], fb[4];
        #pragma unroll
        for (int f = 0; f < 4; ++f) {
            const int aj = wr + f * 16 + r16;
            fa[f].u2[0] = *(const uint2*)(&Aj[buf][aj * KST + g * 8]);
            fa[f].u2[1] = *(const uint2*)(&Aj[buf][aj * KST + g * 8 + 4]);
            const int bn = wc + f * 16 + r16;
            fb[f].u2[0] = *(const uint2*)(&Bn[buf][bn * KST + g * 8]);
            fb[f].u2[1] = *(const uint2*)(&Bn[buf][bn * KST + g * 8 + 4]);
        }
        #pragma unroll
        for (int fi = 0; fi < 4; ++fi)
            #pragma unroll
            for (int fj = 0; fj < 4; ++fj)
                acc[fi][fj] = __builtin_amdgcn_mfma_f32_16x16x32_bf16(fa[fi].v, fb[fj].v, acc[fi][fj], 0, 0, 0);
        if (kt < 15) stage(buf ^ 1);
    }

    #pragma unroll
    for (int fi = 0; fi < 4; ++fi)
        #pragma unroll
        for (int fj = 0; fj < 4; ++fj) {
            const int n = nb + wc + fj * 16 + r16;
            #pragma unroll
            for (int q = 0; q < 4; ++q) {
                const int j = jb + wr + fi * 16 + g * 4 + q;
                out[(size_t)(b * 1024 + 512 + j) * NPIX + n] = acc[fi][fj][q];
            }
        }
}

extern "C" void kernel_launch(void* const* d_in, const int* in_sizes, int n_in,
                              void* d_out, int out_size, void* d_ws, size_t ws_size,
                              hipStream_t stream) {
    const float* x1 = (const float*)d_in[0];
    const float* x2 = (const float*)d_in[1];
    float* out = (float*)d_out;
    (void)in_sizes; (void)n_in; (void)out_size; (void)d_ws; (void)ws_size;

    gemm1_energy<<<dim3(256),  dim3(512), 0, stream>>>(x1, x2, out);
    softmax_rows<<<dim3(8192), dim3(256), 0, stream>>>(out + ATT_OFF);
    gemm2_av    <<<dim3(2048), dim3(256), 0, stream>>>(x1, out);
}

// Round 4
// 235.005 us; speedup vs baseline: 1.5020x; 1.1613x over previous
//
#include <hip/hip_runtime.h>

typedef short bf16x8 __attribute__((ext_vector_type(8)));
typedef float f32x4  __attribute__((ext_vector_type(4)));
typedef unsigned int u32;
typedef unsigned short u16;

#define NBATCH 16
#define C      512
#define NPIX   4096
#define ATT_OFF ((size_t)NBATCH * 1024 * NPIX)   // 67,108,864 floats

typedef __attribute__((address_space(1))) const u32* gp_t;
typedef __attribute__((address_space(3))) u32* lp_t;

// split one f32 pair -> packed bf16 hi pair + bf16 lo pair (truncation split)
__device__ __forceinline__ void splitpair(u32 u0, u32 u1, u32& h, u32& l) {
    h = __builtin_amdgcn_perm(u1, u0, 0x07060302u);
    const u32 m0 = u0 & 0xFFFF0000u, m1 = u1 & 0xFFFF0000u;
    const float l0 = __uint_as_float(u0) - __uint_as_float(m0);
    const float l1 = __uint_as_float(u1) - __uint_as_float(m1);
    l = __builtin_amdgcn_perm(__float_as_uint(l1), __float_as_uint(l0), 0x07060302u);
}

// ---------------------------------------------------------------------------
// GEMM1: energy[b,i,j] = sum_n x1[b,i,n]*x2[b,j,n]  (split-bf16, 3 MFMA)
// 512 blocks (2/CU, independent barriers), block split-K=2.
// f32 tiles staged via global_load_lds (DMA), source-swizzled; split-to-bf16
// happens after ds_read. ks=0 partial -> att slot; ks=1 partial -> park.
// ---------------------------------------------------------------------------
__global__ __launch_bounds__(256, 2) void gemm1_energy(
    const float* __restrict__ x1, const float* __restrict__ x2,
    float* __restrict__ out)
{
    __shared__ __align__(16) float Asm[2][128 * 32];
    __shared__ __align__(16) float Bsm[2][128 * 32];

    const int tid  = threadIdx.x;
    const int lane = tid & 63;
    const int w    = tid >> 6;
    const int wr   = (w >> 1) * 64;
    const int wc   = (w & 1) * 64;
    const int r16  = lane & 15;
    const int g    = lane >> 4;

    const int gid = (blockIdx.x & 7) * 64 + (blockIdx.x >> 3);  // XCD swizzle
    const int b   = gid >> 5;
    const int ib  = ((gid >> 3) & 3) * 128;
    const int jb  = ((gid >> 1) & 3) * 128;
    const int ks  = gid & 1;
    const int ko  = ks * 2048;

    // staging source pointers: issue q covers tile rows w*32+q*8 .. +8
    const int lrow  = lane >> 3;        // 0..7
    const int chunk = lane & 7;         // 16B chunk within 128B row window
    const float* srcA[4];
    const float* srcB[4];
    #pragma unroll
    for (int q = 0; q < 4; ++q) {
        const int row = w * 32 + q * 8 + lrow;
        const int sc  = (chunk ^ ((row >> 1) & 7)) * 4;   // source pre-swizzle
        srcA[q] = x1 + (size_t)(b * C + ib + row) * NPIX + ko + sc;
        srcB[q] = x2 + (size_t)(b * C + jb + row) * NPIX + ko + sc;
    }

    auto stage = [&](int kt, int buf) {
        #pragma unroll
        for (int q = 0; q < 4; ++q) {
            __builtin_amdgcn_global_load_lds((gp_t)(const void*)(srcA[q] + kt * 32),
                                             (lp_t)(void*)&Asm[buf][(w * 32 + q * 8) * 32], 16, 0, 0);
            __builtin_amdgcn_global_load_lds((gp_t)(const void*)(srcB[q] + kt * 32),
                                             (lp_t)(void*)&Bsm[buf][(w * 32 + q * 8) * 32], 16, 0, 0);
        }
    };

    const f32x4 zero4 = {0.f, 0.f, 0.f, 0.f};
    f32x4 acc[4][4];
    #pragma unroll
    for (int i = 0; i < 4; ++i)
        #pragma unroll
        for (int j = 0; j < 4; ++j) acc[i][j] = zero4;

    union B8 { bf16x8 v; u32 u[4]; };

    stage(0, 0);

    for (int kt = 0; kt < 64; ++kt) {
        const int buf = kt & 1;
        __syncthreads();                 // buf fully staged (vmcnt drained)

        B8 ah[4], al[4], bh[4], bl[4];
        uint4 UA[4][2], UB[4][2];
        #pragma unroll
        for (int f = 0; f < 4; ++f) {
            const int ar = wr + f * 16 + r16;
            const float* abase = &Asm[buf][ar * 32];
            UA[f][0] = *(const uint4*)(abase + (((2 * g)     ^ ((ar >> 1) & 7)) * 4));
            UA[f][1] = *(const uint4*)(abase + (((2 * g + 1) ^ ((ar >> 1) & 7)) * 4));
            const int br = wc + f * 16 + r16;
            const float* bbase = &Bsm[buf][br * 32];
            UB[f][0] = *(const uint4*)(bbase + (((2 * g)     ^ ((br >> 1) & 7)) * 4));
            UB[f][1] = *(const uint4*)(bbase + (((2 * g + 1) ^ ((br >> 1) & 7)) * 4));
        }
        if (kt < 63) stage(kt + 1, buf ^ 1);   // DMA flies during convert+MFMA

        #pragma unroll
        for (int f = 0; f < 4; ++f) {
            splitpair(UA[f][0].x, UA[f][0].y, ah[f].u[0], al[f].u[0]);
            splitpair(UA[f][0].z, UA[f][0].w, ah[f].u[1], al[f].u[1]);
            splitpair(UA[f][1].x, UA[f][1].y, ah[f].u[2], al[f].u[2]);
            splitpair(UA[f][1].z, UA[f][1].w, ah[f].u[3], al[f].u[3]);
            splitpair(UB[f][0].x, UB[f][0].y, bh[f].u[0], bl[f].u[0]);
            splitpair(UB[f][0].z, UB[f][0].w, bh[f].u[1], bl[f].u[1]);
            splitpair(UB[f][1].x, UB[f][1].y, bh[f].u[2], bl[f].u[2]);
            splitpair(UB[f][1].z, UB[f][1].w, bh[f].u[3], bl[f].u[3]);
        }

        __builtin_amdgcn_s_setprio(1);
        #pragma unroll
        for (int fi = 0; fi < 4; ++fi)
            #pragma unroll
            for (int fj = 0; fj < 4; ++fj) {
                acc[fi][fj] = __builtin_amdgcn_mfma_f32_16x16x32_bf16(ah[fi].v, bh[fj].v, acc[fi][fj], 0, 0, 0);
                acc[fi][fj] = __builtin_amdgcn_mfma_f32_16x16x32_bf16(ah[fi].v, bl[fj].v, acc[fi][fj], 0, 0, 0);
                acc[fi][fj] = __builtin_amdgcn_mfma_f32_16x16x32_bf16(al[fi].v, bh[fj].v, acc[fi][fj], 0, 0, 0);
            }
        __builtin_amdgcn_s_setprio(0);
    }

    // partial energies: ks=0 -> att slot; ks=1 -> park (front of av region)
    float* dst = (ks == 0) ? (out + ATT_OFF + (size_t)b * C * C)
                           : (out + (size_t)(b * 1024 + 512) * NPIX);
    #pragma unroll
    for (int fi = 0; fi < 4; ++fi)
        #pragma unroll
        for (int fj = 0; fj < 4; ++fj) {
            const int j = jb + wc + fj * 16 + r16;
            #pragma unroll
            for (int q = 0; q < 4; ++q) {
                const int i = ib + wr + fi * 16 + g * 4 + q;
                dst[(size_t)i * C + j] = acc[fi][fj][q];
            }
        }
}

// ---------------------------------------------------------------------------
// Softmax over last dim (512): adds the two split-K partials, softmaxes,
// writes final attention into the att slot.
// ---------------------------------------------------------------------------
__global__ __launch_bounds__(256) void softmax_rows(float* __restrict__ out)
{
    const int bi = blockIdx.x;          // b*512 + i
    const int b  = bi >> 9;
    const int i  = bi & 511;
    float* p        = out + ATT_OFF + (size_t)bi * C;
    const float* pk = out + (size_t)(b * 1024 + 512) * NPIX + (size_t)i * C;

    const int t = threadIdx.x;
    const int lane = t & 63, wid = t >> 6;
    __shared__ float red[8];

    float a = p[t] + pk[t];
    float c = p[t + 256] + pk[t + 256];
    float m = fmaxf(a, c);
    #pragma unroll
    for (int o = 32; o; o >>= 1) m = fmaxf(m, __shfl_xor(m, o));
    if (lane == 0) red[wid] = m;
    __syncthreads();
    m = fmaxf(fmaxf(red[0], red[1]), fmaxf(red[2], red[3]));

    float e0 = __expf(a - m), e1 = __expf(c - m);
    float s = e0 + e1;
    #pragma unroll
    for (int o = 32; o; o >>= 1) s += __shfl_xor(s, o);
    if (lane == 0) red[4 + wid] = s;
    __syncthreads();
    s = (red[4] + red[5]) + (red[6] + red[7]);
    const float inv = 1.0f / s;
    p[t]       = e0 * inv;
    p[t + 256] = e1 * inv;
}

// ---------------------------------------------------------------------------
// GEMM2: av[b,j,n] = sum_k att[b,k,j] * x1[b,k,n]   (TT, K=512, bf16 MFMA)
// Deferred pack (T14): raw f32 loads issued early, pack+ds_write late.
// jt==0 blocks also copy their staged x1 f32 tile to out channels [0,512).
// ---------------------------------------------------------------------------
#define KST 36   // u16 stride per LDS row (32 + 4 pad)

__global__ __launch_bounds__(256, 3) void gemm2_av(
    const float* __restrict__ x1, float* __restrict__ out)
{
    __shared__ __align__(16) u16 Aj[2][128 * KST];  // att^T tile: row j, k 0..31
    __shared__ __align__(16) u16 Bn[2][128 * KST];  // x1^T tile: row n, k 0..31

    const float* att = out + ATT_OFF;
    const int tid  = threadIdx.x;
    const int lane = tid & 63;
    const int wid  = tid >> 6;
    const int wr   = (wid >> 1) * 64;   // j
    const int wc   = (wid & 1) * 64;    // n
    const int r16  = lane & 15;
    const int g    = lane >> 4;

    const int gid = (blockIdx.x & 7) * 256 + (blockIdx.x >> 3);  // XCD swizzle
    const int b   = gid >> 7;
    const int jt  = (gid >> 5) & 3;
    const int nt  = gid & 31;
    const int jb  = jt * 128;
    const int nb  = nt * 128;

    const int col = (tid & 31) * 4;     // j (or n) column group staged
    const int ksr = (tid >> 5) * 4;     // 4 k's per thread per tile

    const float* ap0 = att + (size_t)b * C * C    + (size_t)ksr * C    + jb + col;
    const float* bp0 = x1  + (size_t)b * C * NPIX + (size_t)ksr * NPIX + nb + col;
    float* cpy = out + (size_t)(b * 1024 + ksr) * NPIX + nb + col;

    f32x4 La[4], Lb[4];

    auto loadk = [&](int kt) {
        #pragma unroll
        for (int i = 0; i < 4; ++i) {
            La[i] = *(const f32x4*)(ap0 + (size_t)(kt * 32 + i) * C);
            Lb[i] = *(const f32x4*)(bp0 + (size_t)(kt * 32 + i) * NPIX);
        }
    };

    auto stage = [&](int kt, int buf) {
        u32 sa[8], sb[8];
        #pragma unroll
        for (int jj = 0; jj < 4; ++jj) {
            sa[jj * 2]     = __builtin_amdgcn_perm(__float_as_uint(La[1][jj]), __float_as_uint(La[0][jj]), 0x07060302u);
            sa[jj * 2 + 1] = __builtin_amdgcn_perm(__float_as_uint(La[3][jj]), __float_as_uint(La[2][jj]), 0x07060302u);
            sb[jj * 2]     = __builtin_amdgcn_perm(__float_as_uint(Lb[1][jj]), __float_as_uint(Lb[0][jj]), 0x07060302u);
            sb[jj * 2 + 1] = __builtin_amdgcn_perm(__float_as_uint(Lb[3][jj]), __float_as_uint(Lb[2][jj]), 0x07060302u);
        }
        #pragma unroll
        for (int jj = 0; jj < 4; ++jj) {
            *(uint2*)((char*)Aj[buf] + ((col + jj) * KST + ksr) * 2) = make_uint2(sa[jj * 2], sa[jj * 2 + 1]);
            *(uint2*)((char*)Bn[buf] + ((col + jj) * KST + ksr) * 2) = make_uint2(sb[jj * 2], sb[jj * 2 + 1]);
        }
        if (jt == 0) {                  // fused x1 -> out copy
            #pragma unroll
            for (int i = 0; i < 4; ++i)
                *(f32x4*)(cpy + (size_t)(kt * 32 + i) * NPIX) = Lb[i];
        }
    };

    const f32x4 zero4 = {0.f, 0.f, 0.f, 0.f};
    f32x4 acc[4][4];
    #pragma unroll
    for (int i = 0; i < 4; ++i)
        #pragma unroll
        for (int j = 0; j < 4; ++j) acc[i][j] = zero4;

    loadk(0);
    stage(0, 0);

    for (int kt = 0; kt < 16; ++kt) {
        if (kt < 15) loadk(kt + 1);     // raw loads issued early (T14)
        __syncthreads();
        const int buf = kt & 1;

        union { bf16x8 v; uint2 u2[2]; } fa[4], fb[4];
        #pragma unroll
        for (int f = 0; f < 4; ++f) {
            const int aj = wr + f * 16 + r16;
            fa[f].u2[0] = *(const uint2*)(&Aj[buf][aj * KST + g * 8]);
            fa[f].u2[1] = *(const uint2*)(&Aj[buf][aj * KST + g * 8 + 4]);
            const int bn = wc + f * 16 + r16;
            fb[f].u2[0] = *(const uint2*)(&Bn[buf][bn * KST + g * 8]);
            fb[f].u2[1] = *(const uint2*)(&Bn[buf][bn * KST + g * 8 + 4]);
        }
        __builtin_amdgcn_s_setprio(1);
        #pragma unroll
        for (int fi = 0; fi < 4; ++fi)
            #pragma unroll
            for (int fj = 0; fj < 4; ++fj)
                acc[fi][fj] = __builtin_amdgcn_mfma_f32_16x16x32_bf16(fa[fi].v, fb[fj].v, acc[fi][fj], 0, 0, 0);
        __builtin_amdgcn_s_setprio(0);
        if (kt < 15) stage(kt + 1, buf ^ 1);   // pack+write late (post-MFMA)
    }

    #pragma unroll
    for (int fi = 0; fi < 4; ++fi)
        #pragma unroll
        for (int fj = 0; fj < 4; ++fj) {
            const int n = nb + wc + fj * 16 + r16;
            #pragma unroll
            for (int q = 0; q < 4; ++q) {
                const int j = jb + wr + fi * 16 + g * 4 + q;
                out[(size_t)(b * 1024 + 512 + j) * NPIX + n] = acc[fi][fj][q];
            }
        }
}

extern "C" void kernel_launch(void* const* d_in, const int* in_sizes, int n_in,
                              void* d_out, int out_size, void* d_ws, size_t ws_size,
                              hipStream_t stream) {
    const float* x1 = (const float*)d_in[0];
    const float* x2 = (const float*)d_in[1];
    float* out = (float*)d_out;
    (void)in_sizes; (void)n_in; (void)out_size; (void)d_ws; (void)ws_size;

    gemm1_energy<<<dim3(512),  dim3(256), 0, stream>>>(x1, x2, out);
    softmax_rows<<<dim3(8192), dim3(256), 0, stream>>>(out);
    gemm2_av    <<<dim3(2048), dim3(256), 0, stream>>>(x1, out);
}